// Round 2
// baseline (3139.604 us; speedup 1.0000x reference)
//
#include <hip/hip_runtime.h>
#include <stdint.h>
#include <math.h>

#define BROWS 16384

typedef _Float16 h8 __attribute__((ext_vector_type(8)));
typedef _Float16 h4 __attribute__((ext_vector_type(4)));
typedef __bf16   b8 __attribute__((ext_vector_type(8)));
typedef __bf16   b4 __attribute__((ext_vector_type(4)));
typedef float    f4 __attribute__((ext_vector_type(4)));

typedef __attribute__((address_space(3))) char       lds_char;
typedef __attribute__((address_space(1))) const char gbl_char;

// async global->LDS, 16B per lane; LDS dest = wave-uniform base + lane*16
__device__ __forceinline__ void gload16(const void* g, void* l) {
  __builtin_amdgcn_global_load_lds((const gbl_char*)(uintptr_t)g,
                                   (lds_char*)(uintptr_t)l, 16, 0, 0);
}

// ---------------------------------------------------------------------------
// fp16 2-term split GEMM:  C = A @ W^T (+epilogue), A (M x K) = Ah + Al/2048,
// W (N x K) = Wh + Wl/2048, both row-major, K contiguous.
// EPI 0: y += v0[col]; write split planes Ch/Cl          (p1, p2)
// EPI 1: y = relu(y*v0[col] + v1[col]); write Ch/Cl      (m1, m2)
// EPI 2: Cf = y + v0[col]  (f32)                          (m3)
// ---------------------------------------------------------------------------
template<int EPI>
__global__ __launch_bounds__(256, 2)
void gemm_split(const _Float16* __restrict__ Ah, const _Float16* __restrict__ Al,
                const _Float16* __restrict__ Wh, const _Float16* __restrict__ Wl,
                const int lda, const int ldw, const int K,
                _Float16* __restrict__ Ch, _Float16* __restrict__ Cl,
                float* __restrict__ Cf, const int ldc,
                const float* __restrict__ v0, const float* __restrict__ v1)
{
  __shared__ char smem[32768];
  char* const sAh = smem;
  char* const sAl = smem + 8192;
  char* const sWh = smem + 16384;
  char* const sWl = smem + 24576;

  const int tid  = threadIdx.x;
  const int wid  = tid >> 6, lane = tid & 63;
  const int bm = blockIdx.x, bn = blockIdx.y;
  const int wr = wid >> 1, wc = wid & 1;          // 2x2 waves, 64x64 each
  const int sr  = lane >> 2;                      // staging row-in-16
  const int scb = (lane & 3) * 16;                // staging byte col
  const int fr  = lane & 15;                      // fragment row/col
  const int fcb = (lane >> 4) * 16;               // fragment k byte col

  f4 accA[4][4] = {};
  f4 accB[4][4] = {};

  const size_t arow0 = (size_t)bm * 128;
  const size_t wrow0 = (size_t)bn * 128;

  for (int k0 = 0; k0 < K; k0 += 32) {
    __syncthreads();
#pragma unroll
    for (int i = 0; i < 2; ++i) {
      const int rb = i * 64 + wid * 16;
      const size_t ga = (arow0 + rb + sr) * (size_t)lda + k0;
      const size_t gw = (wrow0 + rb + sr) * (size_t)ldw + k0;
      const int lo = rb * 64;                     // wave-uniform LDS base
      gload16((const char*)(Ah + ga) + scb, sAh + lo);
      gload16((const char*)(Al + ga) + scb, sAl + lo);
      gload16((const char*)(Wh + gw) + scb, sWh + lo);
      gload16((const char*)(Wl + gw) + scb, sWl + lo);
    }
    __syncthreads();

    h8 ah[4], al[4], bh[4], bl[4];
#pragma unroll
    for (int mi = 0; mi < 4; ++mi) {
      const int r = (wr * 64 + mi * 16 + fr) * 64 + fcb;
      ah[mi] = *(const h8*)(sAh + r);
      al[mi] = *(const h8*)(sAl + r);
    }
#pragma unroll
    for (int ni = 0; ni < 4; ++ni) {
      const int r = (wc * 64 + ni * 16 + fr) * 64 + fcb;
      bh[ni] = *(const h8*)(sWh + r);
      bl[ni] = *(const h8*)(sWl + r);
    }
#pragma unroll
    for (int mi = 0; mi < 4; ++mi)
#pragma unroll
      for (int ni = 0; ni < 4; ++ni) {
        accA[mi][ni] = __builtin_amdgcn_mfma_f32_16x16x32_f16(ah[mi], bh[ni], accA[mi][ni], 0, 0, 0);
        accB[mi][ni] = __builtin_amdgcn_mfma_f32_16x16x32_f16(ah[mi], bl[ni], accB[mi][ni], 0, 0, 0);
        accB[mi][ni] = __builtin_amdgcn_mfma_f32_16x16x32_f16(al[mi], bh[ni], accB[mi][ni], 0, 0, 0);
      }
  }

  const int rg = (lane >> 4) * 4;                 // C/D: col=lane&15, row=(lane>>4)*4+j
#pragma unroll
  for (int mi = 0; mi < 4; ++mi)
#pragma unroll
    for (int ni = 0; ni < 4; ++ni) {
      const int gcol = bn * 128 + wc * 64 + ni * 16 + fr;
      const float a0 = v0[gcol];
      const float a1 = (EPI == 1) ? v1[gcol] : 0.f;
#pragma unroll
      for (int j = 0; j < 4; ++j) {
        const size_t grow = arow0 + wr * 64 + mi * 16 + rg + j;
        float y = accA[mi][ni][j] + accB[mi][ni][j] * (1.f / 2048.f);
        const size_t off = grow * (size_t)ldc + gcol;
        if constexpr (EPI == 0) {
          y += a0;
          const _Float16 hh = (_Float16)y;
          Ch[off] = hh;
          Cl[off] = (_Float16)((y - (float)hh) * 2048.f);
        } else if constexpr (EPI == 1) {
          y = fmaxf(fmaf(y, a0, a1), 0.f);
          const _Float16 hh = (_Float16)y;
          Ch[off] = hh;
          Cl[off] = (_Float16)((y - (float)hh) * 2048.f);
        } else {
          Cf[off] = y + a0;
        }
      }
    }
}

// ---------------------------------------------------------------------------
// bf16 GEMM: C = A @ W^T.
// EPI 0 (MoE): Cf = (acc? Cf : 0) + rw[row*8+eidx] * (y + v0[col])
// EPI 1 (fus): Cf = y*v0[col] + v1[col]
// ---------------------------------------------------------------------------
template<int EPI>
__global__ __launch_bounds__(256, 2)
void gemm_bf(const __bf16* __restrict__ A, const __bf16* __restrict__ W,
             const int lda, const int ldw, const int K,
             float* __restrict__ Cf, const int ldc,
             const float* __restrict__ v0, const float* __restrict__ v1,
             const float* __restrict__ rw, const int eidx, const int accflag)
{
  __shared__ char smem[16384];
  char* const sA = smem;
  char* const sW = smem + 8192;

  const int tid  = threadIdx.x;
  const int wid  = tid >> 6, lane = tid & 63;
  const int bm = blockIdx.x, bn = blockIdx.y;
  const int wr = wid >> 1, wc = wid & 1;
  const int sr  = lane >> 2;
  const int scb = (lane & 3) * 16;
  const int fr  = lane & 15;
  const int fcb = (lane >> 4) * 16;

  f4 acc[4][4] = {};

  const size_t arow0 = (size_t)bm * 128;
  const size_t wrow0 = (size_t)bn * 128;

  for (int k0 = 0; k0 < K; k0 += 32) {
    __syncthreads();
#pragma unroll
    for (int i = 0; i < 2; ++i) {
      const int rb = i * 64 + wid * 16;
      const size_t ga = (arow0 + rb + sr) * (size_t)lda + k0;
      const size_t gw = (wrow0 + rb + sr) * (size_t)ldw + k0;
      const int lo = rb * 64;
      gload16((const char*)(A + ga) + scb, sA + lo);
      gload16((const char*)(W + gw) + scb, sW + lo);
    }
    __syncthreads();

    b8 av[4], bv[4];
#pragma unroll
    for (int mi = 0; mi < 4; ++mi)
      av[mi] = *(const b8*)(sA + (wr * 64 + mi * 16 + fr) * 64 + fcb);
#pragma unroll
    for (int ni = 0; ni < 4; ++ni)
      bv[ni] = *(const b8*)(sW + (wc * 64 + ni * 16 + fr) * 64 + fcb);
#pragma unroll
    for (int mi = 0; mi < 4; ++mi)
#pragma unroll
      for (int ni = 0; ni < 4; ++ni)
        acc[mi][ni] = __builtin_amdgcn_mfma_f32_16x16x32_bf16(av[mi], bv[ni], acc[mi][ni], 0, 0, 0);
  }

  const int rg = (lane >> 4) * 4;
#pragma unroll
  for (int mi = 0; mi < 4; ++mi) {
#pragma unroll
    for (int j = 0; j < 4; ++j) {
      const size_t grow = arow0 + wr * 64 + mi * 16 + rg + j;
      float wgt = 0.f;
      if constexpr (EPI == 0) wgt = rw[grow * 8 + eidx];
#pragma unroll
      for (int ni = 0; ni < 4; ++ni) {
        const int gcol = bn * 128 + wc * 64 + ni * 16 + fr;
        const float y = acc[mi][ni][j];
        const size_t off = grow * (size_t)ldc + gcol;
        if constexpr (EPI == 0) {
          float val = wgt * (y + v0[gcol]);
          if (accflag) val += Cf[off];
          Cf[off] = val;
        } else {
          Cf[off] = fmaf(y, v0[gcol], v1[gcol]);
        }
      }
    }
  }
}

// --------------------------- prep / elementwise ----------------------------

__global__ void split_w(const float* __restrict__ src, _Float16* __restrict__ dh,
                        _Float16* __restrict__ dl, const size_t n)
{
  const size_t i = ((size_t)blockIdx.x * 256 + threadIdx.x) * 4;
  if (i >= n) return;
  const f4 v = *(const f4*)(src + i);
  h4 hh, ll;
#pragma unroll
  for (int j = 0; j < 4; ++j) {
    const _Float16 h = (_Float16)v[j];
    hh[j] = h;
    ll[j] = (_Float16)((v[j] - (float)h) * 2048.f);
  }
  *(h4*)(dh + i) = hh;
  *(h4*)(dl + i) = ll;
}

__global__ void cvt_bf(const float* __restrict__ src, __bf16* __restrict__ dst, const size_t n)
{
  const size_t i = ((size_t)blockIdx.x * 256 + threadIdx.x) * 4;
  if (i >= n) return;
  const f4 v = *(const f4*)(src + i);
  b4 o;
#pragma unroll
  for (int j = 0; j < 4; ++j) o[j] = (__bf16)v[j];
  *(b4*)(dst + i) = o;
}

// x1 -> cols [0,1024), x2 -> cols [1024,2048) of split planes (lda 2048)
__global__ void prep_x(const float* __restrict__ x1, const float* __restrict__ x2,
                       _Float16* __restrict__ ph, _Float16* __restrict__ pl)
{
  const size_t i = ((size_t)blockIdx.x * 256 + threadIdx.x) * 4;
  const int b = (int)(i >> 11);
  const int c = (int)(i & 2047);
  const float* s = (c < 1024) ? (x1 + (size_t)b * 1024 + c)
                              : (x2 + (size_t)b * 1024 + (c - 1024));
  const f4 v = *(const f4*)s;
  h4 hh, ll;
#pragma unroll
  for (int j = 0; j < 4; ++j) {
    const _Float16 h = (_Float16)v[j];
    hh[j] = h;
    ll[j] = (_Float16)((v[j] - (float)h) * 2048.f);
  }
  *(h4*)(ph + i) = hh;
  *(h4*)(pl + i) = ll;
}

// fold BN-eval into per-col scale/shift: s = g/sqrt(1+eps), t = mb*s + b
__global__ void fold_kernel(const float* g1, const float* b1, const float* mb1,
                            const float* g2, const float* b2, const float* mb2,
                            const float* gf, const float* bf, const float* fb,
                            float* s1, float* t1, float* s2, float* t2,
                            float* fs, float* ft)
{
  const int t = blockIdx.x * 256 + threadIdx.x;
  const float inv = (float)(1.0 / sqrt(1.0 + 1.0e-5));
  if (t < 2048) {
    float a = g1[t] * inv; s1[t] = a; t1[t] = mb1[t] * a + b1[t];
    float c = g2[t] * inv; s2[t] = c; t2[t] = mb2[t] * c + b2[t];
  }
  if (t < 1024) {
    float a = gf[t] * inv; fs[t] = a; ft[t] = fb[t] * a + bf[t];
  }
}

// LayerNorm over 2048 cols, in-place f32 + bf16 copy
__global__ __launch_bounds__(256)
void ln_kernel(float* __restrict__ xf, __bf16* __restrict__ xb,
               const float* __restrict__ lg, const float* __restrict__ lb)
{
  const int row = blockIdx.x;
  float* xr = xf + (size_t)row * 2048;
  const int tid = threadIdx.x;
  const f4 v0 = *(const f4*)(xr + tid * 4);
  const f4 v1 = *(const f4*)(xr + 1024 + tid * 4);
  double s = 0.0, ss = 0.0;
#pragma unroll
  for (int j = 0; j < 4; ++j) {
    s  += (double)v0[j] + (double)v1[j];
    ss += (double)v0[j] * v0[j] + (double)v1[j] * v1[j];
  }
#pragma unroll
  for (int o = 32; o; o >>= 1) { s += __shfl_xor(s, o); ss += __shfl_xor(ss, o); }
  __shared__ double red[8];
  const int wid = tid >> 6, lane = tid & 63;
  if (!lane) { red[wid] = s; red[4 + wid] = ss; }
  __syncthreads();
  const double S  = red[0] + red[1] + red[2] + red[3];
  const double SS = red[4] + red[5] + red[6] + red[7];
  const double mu = S * (1.0 / 2048.0);
  const double var = SS * (1.0 / 2048.0) - mu * mu;
  const float inv = (float)(1.0 / sqrt(var + 1.0e-5));
  const float muf = (float)mu;
  f4 o0, o1;
  b4 q0, q1;
#pragma unroll
  for (int j = 0; j < 4; ++j) {
    const int c0 = tid * 4 + j, c1 = 1024 + tid * 4 + j;
    o0[j] = (v0[j] - muf) * inv * lg[c0] + lb[c0];
    o1[j] = (v1[j] - muf) * inv * lg[c1] + lb[c1];
    q0[j] = (__bf16)o0[j];
    q1[j] = (__bf16)o1[j];
  }
  *(f4*)(xr + tid * 4) = o0;
  *(f4*)(xr + 1024 + tid * 4) = o1;
  *(b4*)(xb + (size_t)row * 2048 + tid * 4) = q0;
  *(b4*)(xb + (size_t)row * 2048 + 1024 + tid * 4) = q1;
}

// gate: per row, f64 logits -> top2 -> softmax -> dense per-expert weights
__global__ __launch_bounds__(256)
void gate_kernel(const float* __restrict__ xf,
                 const float* __restrict__ gw, const float* __restrict__ gb,
                 float* __restrict__ wsel)
{
  __shared__ float lgw[8192];
  const int tid = threadIdx.x;
#pragma unroll
  for (int i = 0; i < 8; ++i) {
    const int idx = (tid + 256 * i) * 4;
    *(f4*)(lgw + idx) = *(const f4*)(gw + idx);
  }
  __syncthreads();
  const int wid = tid >> 6, lane = tid & 63;
  const int row = blockIdx.x * 4 + wid;
  const float* xr = xf + (size_t)row * 2048;
  double acc[8] = {0, 0, 0, 0, 0, 0, 0, 0};
  for (int i = 0; i < 16; ++i) {
    const int d = lane + 64 * i;
    const double xv = (double)xr[d];
#pragma unroll
    for (int e = 0; e < 8; ++e) acc[e] += xv * (double)lgw[e * 1024 + d];
  }
#pragma unroll
  for (int e = 0; e < 8; ++e)
#pragma unroll
    for (int o = 32; o; o >>= 1) acc[e] += __shfl_xor(acc[e], o);
  if (lane == 0) {
    double lg[8];
#pragma unroll
    for (int e = 0; e < 8; ++e) lg[e] = acc[e] + (double)gb[e];
    int i0 = 0;
    for (int e = 1; e < 8; ++e) if (lg[e] > lg[i0]) i0 = e;
    int i1 = -1;
    for (int e = 0; e < 8; ++e) if (e != i0 && (i1 < 0 || lg[e] > lg[i1])) i1 = e;
    const double p = exp(lg[i1] - lg[i0]);
    const double z = 1.0 + p;
    const float w0 = (float)(1.0 / z), w1 = (float)(p / z);
    for (int e = 0; e < 8; ++e)
      wsel[(size_t)row * 8 + e] = (e == i0) ? w0 : ((e == i1) ? w1 : 0.f);
  }
}

// out[row] = dot(fused_row, reg_w) + reg_b
__global__ __launch_bounds__(256)
void reg_kernel(const float* __restrict__ xf, const float* __restrict__ rw,
                const float* __restrict__ rb, float* __restrict__ out)
{
  const int wid = threadIdx.x >> 6, lane = threadIdx.x & 63;
  const int row = blockIdx.x * 4 + wid;
  const float* xr = xf + (size_t)row * 1024;
  double acc = 0.0;
#pragma unroll
  for (int i = 0; i < 4; ++i) {
    const int f = (lane + 64 * i) * 4;
    const f4 a = *(const f4*)(xr + f);
    const f4 w = *(const f4*)(rw + f);
    acc += (double)a[0] * w[0] + (double)a[1] * w[1] + (double)a[2] * w[2] + (double)a[3] * w[3];
  }
#pragma unroll
  for (int o = 32; o; o >>= 1) acc += __shfl_xor(acc, o);
  if (!lane) out[row] = (float)(acc + (double)rb[0]);
}

// ---------------------------------------------------------------------------

extern "C" void kernel_launch(void* const* d_in, const int* in_sizes, int n_in,
                              void* d_out, int out_size, void* d_ws, size_t ws_size,
                              hipStream_t stream)
{
  (void)in_sizes; (void)n_in; (void)out_size;
  const float* x1    = (const float*)d_in[0];
  const float* x2    = (const float*)d_in[1];
  const float* p1_w  = (const float*)d_in[2];
  const float* p1_b  = (const float*)d_in[3];
  const float* p2_w  = (const float*)d_in[4];
  const float* p2_b  = (const float*)d_in[5];
  const float* m1_w  = (const float*)d_in[6];
  const float* bn1_g = (const float*)d_in[8];
  const float* bn1_b = (const float*)d_in[9];
  const float* m1_b  = (const float*)d_in[7];
  const float* m2_w  = (const float*)d_in[10];
  const float* m2_b  = (const float*)d_in[11];
  const float* bn2_g = (const float*)d_in[12];
  const float* bn2_b = (const float*)d_in[13];
  const float* m3_w  = (const float*)d_in[14];
  const float* m3_b  = (const float*)d_in[15];
  const float* ln_g  = (const float*)d_in[16];
  const float* ln_b  = (const float*)d_in[17];
  const float* ex_w  = (const float*)d_in[18];
  const float* ex_b  = (const float*)d_in[19];
  const float* gate_w= (const float*)d_in[20];
  const float* gate_b= (const float*)d_in[21];
  const float* fus_w = (const float*)d_in[22];
  const float* fus_b = (const float*)d_in[23];
  const float* bnf_g = (const float*)d_in[24];
  const float* bnf_b = (const float*)d_in[25];
  const float* reg_w = (const float*)d_in[26];
  const float* reg_b = (const float*)d_in[27];

  char* ws = (char*)d_ws;
  size_t off = 0;
  auto alloc = [&](size_t bytes) { size_t o = off; off += (bytes + 255) & ~(size_t)255; return o; };

  // ---- fixed region: converted weights + folded vectors (~80 MB) ----
  const size_t oWHp1 = alloc((size_t)1048576 * 2), oWLp1 = alloc((size_t)1048576 * 2);
  const size_t oWHp2 = alloc((size_t)1048576 * 2), oWLp2 = alloc((size_t)1048576 * 2);
  const size_t oWHm1 = alloc((size_t)4194304 * 2), oWLm1 = alloc((size_t)4194304 * 2);
  const size_t oWHm2 = alloc((size_t)4194304 * 2), oWLm2 = alloc((size_t)4194304 * 2);
  const size_t oWHm3 = alloc((size_t)4194304 * 2), oWLm3 = alloc((size_t)4194304 * 2);
  const size_t oWBex = alloc((size_t)8388608 * 2);
  const size_t oWBfu = alloc((size_t)2097152 * 2);
  const size_t oS1 = alloc(2048 * 4), oT1 = alloc(2048 * 4);
  const size_t oS2 = alloc(2048 * 4), oT2 = alloc(2048 * 4);
  const size_t oFS = alloc(1024 * 4), oFT = alloc(1024 * 4);
  const size_t fixedEnd = off;

  // ---- choose row-chunk C so activations fit the actual ws_size ----
  int C = BROWS;
  while (C > 512) {
    const size_t need = fixedEnd + 4 * ((size_t)C * 4096 + 256)  // 4 fp16 planes C x 2048
                        + 2 * ((size_t)C * 32 + 256) + 4096;     // 2 wsel
    if (ws_size >= need) break;
    C >>= 1;
  }

  // ---- per-chunk activation region ----
  const size_t oPH0 = alloc((size_t)C * 4096);   // region X (also F32 alias)
  const size_t oPL0 = alloc((size_t)C * 4096);
  const size_t oPH1 = alloc((size_t)C * 4096);   // region Y (also BFA alias)
  const size_t oPL1 = alloc((size_t)C * 4096);   // (also BFB alias)
  const size_t oWS1 = alloc((size_t)C * 32);
  const size_t oWS2 = alloc((size_t)C * 32);

  _Float16* WHp1 = (_Float16*)(ws + oWHp1); _Float16* WLp1 = (_Float16*)(ws + oWLp1);
  _Float16* WHp2 = (_Float16*)(ws + oWHp2); _Float16* WLp2 = (_Float16*)(ws + oWLp2);
  _Float16* WHm1 = (_Float16*)(ws + oWHm1); _Float16* WLm1 = (_Float16*)(ws + oWLm1);
  _Float16* WHm2 = (_Float16*)(ws + oWHm2); _Float16* WLm2 = (_Float16*)(ws + oWLm2);
  _Float16* WHm3 = (_Float16*)(ws + oWHm3); _Float16* WLm3 = (_Float16*)(ws + oWLm3);
  __bf16* WBex = (__bf16*)(ws + oWBex);
  __bf16* WBfu = (__bf16*)(ws + oWBfu);
  _Float16* PH0 = (_Float16*)(ws + oPH0); _Float16* PL0 = (_Float16*)(ws + oPL0);
  _Float16* PH1 = (_Float16*)(ws + oPH1); _Float16* PL1 = (_Float16*)(ws + oPL1);
  float* F32 = (float*)(ws + oPH0);         // C x 2048 f32 alias over PH0+PL0
  __bf16* BFA = (__bf16*)(ws + oPH1);       // xm bf16 (after m3+LN)
  __bf16* BFB = (__bf16*)(ws + oPL1);       // moe concat bf16
  float* wsel1 = (float*)(ws + oWS1); float* wsel2 = (float*)(ws + oWS2);
  float* s1v = (float*)(ws + oS1); float* t1v = (float*)(ws + oT1);
  float* s2v = (float*)(ws + oS2); float* t2v = (float*)(ws + oT2);
  float* fsv = (float*)(ws + oFS); float* ftv = (float*)(ws + oFT);

  const dim3 T(256);
  // ---- once: fold BN vectors, convert/split all weights ----
  fold_kernel<<<8, T, 0, stream>>>(bn1_g, bn1_b, m1_b, bn2_g, bn2_b, m2_b,
                                   bnf_g, bnf_b, fus_b, s1v, t1v, s2v, t2v, fsv, ftv);
  split_w<<<1024, T, 0, stream>>>(p1_w, WHp1, WLp1, 1048576);
  split_w<<<1024, T, 0, stream>>>(p2_w, WHp2, WLp2, 1048576);
  split_w<<<4096, T, 0, stream>>>(m1_w, WHm1, WLm1, 4194304);
  split_w<<<4096, T, 0, stream>>>(m2_w, WHm2, WLm2, 4194304);
  split_w<<<4096, T, 0, stream>>>(m3_w, WHm3, WLm3, 4194304);
  cvt_bf<<<8192, T, 0, stream>>>(ex_w, WBex, 8388608);
  cvt_bf<<<2048, T, 0, stream>>>(fus_w, WBfu, 2097152);

  // ---- per-chunk pipeline ----
  const dim3 GA(C / 128, 8), GB(C / 128, 16);
  for (int r0 = 0; r0 < BROWS; r0 += C) {
    prep_x<<<C * 2, T, 0, stream>>>(x1 + (size_t)r0 * 1024, x2 + (size_t)r0 * 1024, PH0, PL0);

    // trunk (fp32-faithful via fp16 2-term split)
    gemm_split<0><<<GA, T, 0, stream>>>(PH0, PL0, WHp1, WLp1, 2048, 1024, 1024,
                                        PH1, PL1, nullptr, 2048, p1_b, nullptr);
    gemm_split<0><<<GA, T, 0, stream>>>(PH0 + 1024, PL0 + 1024, WHp2, WLp2, 2048, 1024, 1024,
                                        PH1 + 1024, PL1 + 1024, nullptr, 2048, p2_b, nullptr);
    gemm_split<1><<<GB, T, 0, stream>>>(PH1, PL1, WHm1, WLm1, 2048, 2048, 2048,
                                        PH0, PL0, nullptr, 2048, s1v, t1v);
    gemm_split<1><<<GB, T, 0, stream>>>(PH0, PL0, WHm2, WLm2, 2048, 2048, 2048,
                                        PH1, PL1, nullptr, 2048, s2v, t2v);
    gemm_split<2><<<GB, T, 0, stream>>>(PH1, PL1, WHm3, WLm3, 2048, 2048, 2048,
                                        nullptr, nullptr, F32, 2048, m3_b, nullptr);
    ln_kernel<<<C, T, 0, stream>>>(F32, BFA, ln_g, ln_b);
    gate_kernel<<<C / 4, T, 0, stream>>>(F32,        gate_w, gate_b, wsel1);
    gate_kernel<<<C / 4, T, 0, stream>>>(F32 + 1024, gate_w, gate_b, wsel2);
    // dense experts (bf16), weighted-accumulate epilogue; w=0 for unselected
    for (int e = 0; e < 8; ++e)
      gemm_bf<0><<<GA, T, 0, stream>>>(BFA, WBex + (size_t)e * 1048576, 2048, 1024, 1024,
                                       F32, 2048, ex_b + e * 1024, nullptr, wsel1, e, e ? 1 : 0);
    for (int e = 0; e < 8; ++e)
      gemm_bf<0><<<GA, T, 0, stream>>>(BFA + 1024, WBex + (size_t)e * 1048576, 2048, 1024, 1024,
                                       F32 + 1024, 2048, ex_b + e * 1024, nullptr, wsel2, e, e ? 1 : 0);
    cvt_bf<<<C * 2, T, 0, stream>>>(F32, BFB, (size_t)C * 2048);
    gemm_bf<1><<<GA, T, 0, stream>>>(BFB, WBfu, 2048, 2048, 2048,
                                     F32, 1024, fsv, ftv, nullptr, 0, 0);
    reg_kernel<<<C / 4, T, 0, stream>>>(F32, reg_w, reg_b, (float*)d_out + r0);
  }
}